// Round 2
// baseline (57421.021 us; speedup 1.0000x reference)
//
#include <hip/hip_runtime.h>
#include <math.h>

typedef float f32x2 __attribute__((ext_vector_type(2)));
typedef float f32x4 __attribute__((ext_vector_type(4)));

#define LOG2E 1.4426950408889634f

__device__ __forceinline__ float rcp_fast(float x)  { return __builtin_amdgcn_rcpf(x); }
__device__ __forceinline__ float exp2_fast(float x) { return __builtin_amdgcn_exp2f(x); }
__device__ __forceinline__ float exp_fast(float x)  { return exp2_fast(x * LOG2E); }

// tanh(x) = 1 - 2/(e^{2x}+1).  Saturates correctly at +-1 without clamps.
__device__ __forceinline__ float tanh_fast(float x) {
    float e = exp2_fast(x * (2.0f * LOG2E));
    return 1.0f - 2.0f * rcp_fast(e + 1.0f);
}
// 0.5*(tanh(5x)+1) == sigmoid(10x) exactly.
__device__ __forceinline__ float step_fast(float x) {
    return rcp_fast(1.0f + exp2_fast(x * (-10.0f * LOG2E)));
}
__device__ __forceinline__ float sinh_fast(float x) {
    float e = exp2_fast(x * LOG2E);
    return 0.5f * e - 0.5f * rcp_fast(e);
}

__device__ __forceinline__ f32x2 mk2(float a, float b) { f32x2 r; r.x = a; r.y = b; return r; }

// acc = fma(a, b, acc) packed (2 f32 lanes) — one VALU instruction.
__device__ __forceinline__ void pk_fma(f32x2& acc, f32x2 a, f32x2 b) {
    asm("v_pk_fma_f32 %0, %1, %2, %0" : "+v"(acc) : "v"(a), "v"(b));
}

// Full 64-lane sum via DPP (VALU-speed, no LDS). Result uniform (SGPR).
#define DPP_ADD(x, ctrl, rmask)                                                         \
    x += __builtin_bit_cast(float, __builtin_amdgcn_update_dpp(                         \
             0, __builtin_bit_cast(int, x), ctrl, rmask, 0xf, true))

__device__ __forceinline__ float wave_sum64(float x) {
    DPP_ADD(x, 0x111, 0xf);   // row_shr:1
    DPP_ADD(x, 0x112, 0xf);   // row_shr:2
    DPP_ADD(x, 0x114, 0xf);   // row_shr:4
    DPP_ADD(x, 0x118, 0xf);   // row_shr:8  -> lane15 of each row16 = row sum
    DPP_ADD(x, 0x142, 0xa);   // row_bcast:15 -> lane31 = sum(0..31), lane63 = sum(32..63)
    DPP_ADD(x, 0x143, 0xc);   // row_bcast:31 -> lane63 = total
    return __builtin_bit_cast(float, __builtin_amdgcn_readlane(__builtin_bit_cast(int, x), 63));
}

#define CHUNK 1024

// ---------------------------------------------------------------------------
// RK4 scan: ONE wave (64 threads), zero __syncthreads. Thread j owns MLP
// columns j and j+64. Layer2 via v_pk_fma_f32; reductions via DPP.
// ---------------------------------------------------------------------------
extern "C" __global__ void __launch_bounds__(64, 1)
scan_kernel(const float* __restrict__ x,
            const float* __restrict__ precp,
            const float* __restrict__ temp,
            const float* __restrict__ lday,
            const float* __restrict__ W1, const float* __restrict__ b1,
            const float* __restrict__ W2, const float* __restrict__ b2,
            const float* __restrict__ W3, const float* __restrict__ b3,
            float* __restrict__ sol, int T)
{
    const int j = threadIdx.x;            // 0..63

    __shared__ __align__(16) float h1s[128];
    __shared__ float pr_s[CHUNK + 1], tm_s[CHUNK + 1], ld_s[CHUNK + 1];

    // ---- preload weights (all statically indexed -> registers) ----
    float w1a[4], w1b[4];
#pragma unroll
    for (int i = 0; i < 4; ++i) {
        w1a[i] = W1[i * 128 + j];
        w1b[i] = W1[i * 128 + j + 64];
    }
    const float b1a = b1[j], b1b = b1[j + 64];

    f32x2 w2a[64], w2b[64];               // K-paired columns: 256 VGPRs
#pragma unroll
    for (int k = 0; k < 64; ++k) {
        w2a[k] = mk2(W2[(2 * k) * 128 + j],      W2[(2 * k + 1) * 128 + j]);
        w2b[k] = mk2(W2[(2 * k) * 128 + j + 64], W2[(2 * k + 1) * 128 + j + 64]);
    }
    const float b2a = b2[j], b2b = b2[j + 64];

    float w3a[5], w3b[5];
#pragma unroll
    for (int k = 0; k < 5; ++k) {
        w3a[k] = W3[j * 5 + k];
        w3b[k] = W3[(j + 64) * 5 + k];
    }
    const float b30 = b3[0], b31 = b3[1], b32 = b3[2], b33 = b3[3], b34 = b3[4];

    float S0 = x[0], S1 = x[1];
    if (j == 0) { sol[0] = S0; sol[1] = S1; }

    // rhs: uniform in, uniform out
    auto rhs = [&](float z0, float z1, float pr, float tm, float ld,
                   float& d0, float& d1) {
        // layer 1 (2 columns)
        float aa = b1a, ab = b1b;
        aa = fmaf(z0, w1a[0], aa);  ab = fmaf(z0, w1b[0], ab);
        aa = fmaf(z1, w1a[1], aa);  ab = fmaf(z1, w1b[1], ab);
        aa = fmaf(pr, w1a[2], aa);  ab = fmaf(pr, w1b[2], ab);
        aa = fmaf(tm, w1a[3], aa);  ab = fmaf(tm, w1b[3], ab);
        h1s[j]      = tanh_fast(aa);
        h1s[j + 64] = tanh_fast(ab);
        __builtin_amdgcn_wave_barrier();           // order: writes before reads

        // layer 2: LDS broadcast reads (conflict-free) + packed FMAs
        f32x2 aca0 = mk2(0.f, 0.f), aca1 = mk2(0.f, 0.f);
        f32x2 acb0 = mk2(0.f, 0.f), acb1 = mk2(0.f, 0.f);
#pragma unroll
        for (int m = 0; m < 32; ++m) {
            f32x4 hv = *reinterpret_cast<const f32x4*>(&h1s[4 * m]);
            f32x2 h01 = hv.xy;
            f32x2 h23 = hv.zw;
            pk_fma(aca0, h01, w2a[2 * m]);
            pk_fma(aca1, h23, w2a[2 * m + 1]);
            pk_fma(acb0, h01, w2b[2 * m]);
            pk_fma(acb1, h23, w2b[2 * m + 1]);
        }
        __builtin_amdgcn_wave_barrier();
        f32x2 sa = aca0 + aca1;
        f32x2 sb = acb0 + acb1;
        const float h2a = tanh_fast(sa.x + sa.y + b2a);
        const float h2b = tanh_fast(sb.x + sb.y + b2b);

        // layer 3: per-thread partials -> DPP wave sum (uniform result)
        float o0, o1, o2, o3, o4;
        {
            float p0 = fmaf(h2b, w3b[0], h2a * w3a[0]);
            float p1 = fmaf(h2b, w3b[1], h2a * w3a[1]);
            float p2 = fmaf(h2b, w3b[2], h2a * w3a[2]);
            float p3 = fmaf(h2b, w3b[3], h2a * w3a[3]);
            float p4 = fmaf(h2b, w3b[4], h2a * w3a[4]);
            o0 = wave_sum64(p0) + b30;
            o1 = wave_sum64(p1) + b31;
            o2 = wave_sum64(p2) + b32;
            o3 = wave_sum64(p3) + b33;
            o4 = wave_sum64(p4) + b34;
        }

        // epilogue (uniform, redundantly on all lanes)
        const float sS0 = step_fast(z0);
        const float sS1 = step_fast(z1);
        const float sNT = step_fast(-tm);
        const float melt = sS0 * sinh_fast(o2);    // relu(step)=step (>0)
        d0 = fmaxf(sinh_fast(o3) * sNT, 0.0f) - melt;
        d1 = fmaxf(sinh_fast(o4), 0.0f) + melt
             - sS1 * fmaf(ld, exp_fast(o0), exp_fast(o1));
    };

    // rolling register prefetch of the series (B of step n == A of step n+1)
    float pB = precp[0], tB = temp[0], lB = lday[0];

    for (int cbase = 0; cbase < T - 1; cbase += CHUNK) {
        // stage chunk [cbase, cbase+CHUNK] of the series into LDS
        for (int i = j; i <= CHUNK; i += 64) {
            int g = cbase + i;
            if (g < T) {
                pr_s[i] = precp[g];
                tm_s[i] = temp[g];
                ld_s[i] = lday[g];
            }
        }
        __builtin_amdgcn_wave_barrier();

        const int len = min(T - 1 - cbase, CHUNK);
#pragma unroll 1
        for (int l = 0; l < len; ++l) {
            const float pA = pB, tA = tB, lA = lB;
            // next-step values: needed first ~600cy from now (k2 midpoint)
            pB = pr_s[l + 1];
            tB = tm_s[l + 1];
            lB = ld_s[l + 1];
            const float pM = 0.5f * (pA + pB);
            const float tM = 0.5f * (tA + tB);
            const float lM = 0.5f * (lA + lB);

            float k10, k11, k20, k21, k30, k31, k40, k41;
            rhs(S0, S1, pA, tA, lA, k10, k11);                               // h = 1
            rhs(fmaf(0.5f, k10, S0), fmaf(0.5f, k11, S1), pM, tM, lM, k20, k21);
            rhs(fmaf(0.5f, k20, S0), fmaf(0.5f, k21, S1), pM, tM, lM, k30, k31);
            rhs(k30 + S0,            k31 + S1,            pB, tB, lB, k40, k41);

            const float c = 1.0f / 6.0f;
            S0 = S0 + c * (k10 + 2.0f * (k20 + k30) + k40);
            S1 = S1 + c * (k11 + 2.0f * (k21 + k31) + k41);
            if (j == 0) {
                const int n = cbase + l;
                sol[2 * (n + 1)]     = S0;
                sol[2 * (n + 1) + 1] = S1;
            }
        }
    }
}

// ---------------------------------------------------------------------------
// Output: y[t] = exp(mlp([sol0,sol1,x2,x3])[1]) — fully parallel, tiny.
// ---------------------------------------------------------------------------
extern "C" __global__ void __launch_bounds__(128)
out_kernel(const float* __restrict__ x,
           const float* __restrict__ sol,
           const float* __restrict__ W1, const float* __restrict__ b1,
           const float* __restrict__ W2, const float* __restrict__ b2,
           const float* __restrict__ W3, const float* __restrict__ b3,
           float* __restrict__ y, int T)
{
    const int j    = threadIdx.x;
    const int lane = j & 63;
    const int wv   = j >> 6;

    __shared__ __align__(16) float h1s[128];
    __shared__ float red[2];

    float w1c[4], w2c[128];
#pragma unroll
    for (int i = 0; i < 4; ++i)   w1c[i] = W1[i * 128 + j];
    const float b1j = b1[j];
#pragma unroll
    for (int i = 0; i < 128; ++i) w2c[i] = W2[i * 128 + j];
    const float b2j = b2[j];
    const float w31 = W3[j * 5 + 1];
    const float b31 = b3[1];

#pragma unroll 1
    for (int r = blockIdx.x; r < T; r += gridDim.x) {
        const float z0 = sol[2 * r], z1 = sol[2 * r + 1];
        const float z2 = x[4 * r + 2], z3 = x[4 * r + 3];
        float a = b1j;
        a = fmaf(z0, w1c[0], a);
        a = fmaf(z1, w1c[1], a);
        a = fmaf(z2, w1c[2], a);
        a = fmaf(z3, w1c[3], a);
        h1s[j] = tanh_fast(a);
        __syncthreads();
        float acc0 = 0.f, acc1 = 0.f, acc2 = 0.f, acc3 = 0.f;
#pragma unroll
        for (int i = 0; i < 128; i += 4) {
            const float4 hv = *reinterpret_cast<const float4*>(&h1s[i]);
            acc0 = fmaf(hv.x, w2c[i + 0], acc0);
            acc1 = fmaf(hv.y, w2c[i + 1], acc1);
            acc2 = fmaf(hv.z, w2c[i + 2], acc2);
            acc3 = fmaf(hv.w, w2c[i + 3], acc3);
        }
        const float h2 = tanh_fast(((acc0 + acc1) + (acc2 + acc3)) + b2j);
        float p = h2 * w31;
#pragma unroll
        for (int off = 32; off >= 1; off >>= 1)
            p += __shfl_xor(p, off);
        if (lane == 0) red[wv] = p;
        __syncthreads();
        if (j == 0) y[r] = exp_fast(red[0] + red[1] + b31);
        __syncthreads();
    }
}

// ---------------------------------------------------------------------------
extern "C" void kernel_launch(void* const* d_in, const int* in_sizes, int n_in,
                              void* d_out, int out_size, void* d_ws, size_t ws_size,
                              hipStream_t stream)
{
    const float* x      = (const float*)d_in[0];
    // d_in[1] = t_eval = arange(T)  -> h == 1.0 (same assumption as interp indexing)
    // d_in[2] = t_grid = arange(T)
    const float* precp  = (const float*)d_in[3];
    const float* temp   = (const float*)d_in[4];
    const float* lday   = (const float*)d_in[5];
    const float* W1     = (const float*)d_in[6];
    const float* b1     = (const float*)d_in[7];
    const float* W2     = (const float*)d_in[8];
    const float* b2     = (const float*)d_in[9];
    const float* W3     = (const float*)d_in[10];
    const float* b3     = (const float*)d_in[11];
    float*       y      = (float*)d_out;
    float*       sol    = (float*)d_ws;      // T*2 floats
    const int    T      = in_sizes[1];

    hipLaunchKernelGGL(scan_kernel, dim3(1), dim3(64), 0, stream,
                       x, precp, temp, lday,
                       W1, b1, W2, b2, W3, b3, sol, T);
    hipLaunchKernelGGL(out_kernel, dim3(256), dim3(128), 0, stream,
                       x, sol, W1, b1, W2, b2, W3, b3, y, T);
}

// Round 3
// 23544.296 us; speedup vs baseline: 2.4389x; 2.4389x over previous
//
#include <hip/hip_runtime.h>
#include <math.h>

typedef float f32x2 __attribute__((ext_vector_type(2)));
typedef float f32x4 __attribute__((ext_vector_type(4)));

#define LOG2E 1.4426950408889634f

__device__ __forceinline__ float rcp_fast(float x)  { return __builtin_amdgcn_rcpf(x); }
__device__ __forceinline__ float exp2_fast(float x) { return __builtin_amdgcn_exp2f(x); }
__device__ __forceinline__ float exp_fast(float x)  { return exp2_fast(x * LOG2E); }

// tanh(x) = 1 - 2/(e^{2x}+1). Saturates correctly at +-1.
__device__ __forceinline__ float tanh_fast(float x) {
    float e = exp2_fast(x * (2.0f * LOG2E));
    return 1.0f - 2.0f * rcp_fast(e + 1.0f);
}
// 0.5*(tanh(5x)+1) == sigmoid(10x)
__device__ __forceinline__ float step_fast(float x) {
    return rcp_fast(1.0f + exp2_fast(x * (-10.0f * LOG2E)));
}
__device__ __forceinline__ float sinh_fast(float x) {
    float e = exp2_fast(x * LOG2E);
    return 0.5f * e - 0.5f * rcp_fast(e);
}

__device__ __forceinline__ f32x2 mk2(float a, float b) { f32x2 r; r.x = a; r.y = b; return r; }

// acc = fma(a, b, acc) packed — one VALU instruction.
__device__ __forceinline__ void pk_fma(f32x2& acc, f32x2 a, f32x2 b) {
    asm("v_pk_fma_f32 %0, %1, %2, %0" : "+v"(acc) : "v"(a), "v"(b));
}

#define DPP_ADD(x, ctrl, rmask)                                                         \
    x += __builtin_bit_cast(float, __builtin_amdgcn_update_dpp(                         \
             0, __builtin_bit_cast(int, x), ctrl, rmask, 0xf, true))

// lane pair exchange (xor 1) via quad_perm [1,0,3,2] = 0xB1
__device__ __forceinline__ float dpp_xor1(float x) {
    return __builtin_bit_cast(float, __builtin_amdgcn_update_dpp(
               0, __builtin_bit_cast(int, x), 0xB1, 0xf, 0xf, true));
}

// Full 64-lane sum via DPP; total lands in lane 63 -> readlane -> uniform.
__device__ __forceinline__ float wave_sum64(float x) {
    DPP_ADD(x, 0x111, 0xf);   // row_shr:1
    DPP_ADD(x, 0x112, 0xf);   // row_shr:2
    DPP_ADD(x, 0x114, 0xf);   // row_shr:4
    DPP_ADD(x, 0x118, 0xf);   // row_shr:8
    DPP_ADD(x, 0x142, 0xa);   // row_bcast:15
    DPP_ADD(x, 0x143, 0xc);   // row_bcast:31
    return __builtin_bit_cast(float, __builtin_amdgcn_readlane(__builtin_bit_cast(int, x), 63));
}

#define CHUNK 1024

// ---------------------------------------------------------------------------
// RK4 scan: 256 threads = 4 waves = all 4 SIMDs of one CU.
// tid -> column j = tid>>1 (0..127), K-half kh = tid&1.
// Layer2: 32 pk_fma over own K-half; pair-combine via DPP xor1 (no barrier).
// Layer3: per-wave DPP sum + one 5-float LDS write/wave + barrier.
// Exactly 2 __syncthreads per rhs.
// ---------------------------------------------------------------------------
extern "C" __global__ void __launch_bounds__(256, 1)
scan_kernel(const float* __restrict__ x,
            const float* __restrict__ precp,
            const float* __restrict__ temp,
            const float* __restrict__ lday,
            const float* __restrict__ W1, const float* __restrict__ b1,
            const float* __restrict__ W2, const float* __restrict__ b2,
            const float* __restrict__ W3, const float* __restrict__ b3,
            float* __restrict__ sol, int T)
{
    const int tid  = threadIdx.x;     // 0..255
    const int lane = tid & 63;
    const int w    = tid >> 6;        // wave 0..3
    const int j    = tid >> 1;        // MLP column 0..127
    const int kh   = tid & 1;         // K-half 0/1

    __shared__ __align__(16) float h1s[128];
    __shared__ __align__(16) float red5[5][4];   // [output][wave]
    __shared__ float pr_s[CHUNK + 1], tm_s[CHUNK + 1], ld_s[CHUNK + 1];

    // ---- preload weights (statically indexed -> registers) ----
    float w1c[4];
#pragma unroll
    for (int i = 0; i < 4; ++i) w1c[i] = W1[i * 128 + j];
    const float b1j = b1[j];

    f32x2 w2r[32];                    // own K-half of column j: 64 VGPRs
#pragma unroll
    for (int m = 0; m < 32; ++m) {
        const int k0 = (kh << 6) + 2 * m;
        w2r[m] = mk2(W2[k0 * 128 + j], W2[(k0 + 1) * 128 + j]);
    }
    const float b2j = b2[j];

    float w3r[5];                     // kh=1 lanes masked to 0 (avoid double count)
#pragma unroll
    for (int c = 0; c < 5; ++c) w3r[c] = (kh == 0) ? W3[j * 5 + c] : 0.0f;
    const float b30 = b3[0], b31 = b3[1], b32 = b3[2], b33 = b3[3], b34 = b3[4];

    float S0 = x[0], S1 = x[1];
    if (tid == 0) { sol[0] = S0; sol[1] = S1; }

    auto rhs = [&](float z0, float z1, float pr, float tm, float ld,
                   float& d0, float& d1) {
        // uniform transcendentals independent of the MLP — off the critical chain
        const float sS0 = step_fast(z0);
        const float sS1 = step_fast(z1);
        const float sNT = step_fast(-tm);

        // layer 1
        float a = b1j;
        a = fmaf(z0, w1c[0], a);
        a = fmaf(z1, w1c[1], a);
        a = fmaf(pr, w1c[2], a);
        a = fmaf(tm, w1c[3], a);
        h1s[j] = tanh_fast(a);        // both kh lanes write same value — benign
        __syncthreads();                                   // B1

        // layer 2: own K-half (64 values), broadcast LDS reads
        const int base = kh << 6;
        f32x2 acc0 = mk2(0.f, 0.f), acc1 = mk2(0.f, 0.f);
#pragma unroll
        for (int m = 0; m < 16; ++m) {
            f32x4 hv = *reinterpret_cast<const f32x4*>(&h1s[base + 4 * m]);
            pk_fma(acc0, hv.xy, w2r[2 * m]);
            pk_fma(acc1, hv.zw, w2r[2 * m + 1]);
        }
        float s = (acc0.x + acc0.y) + (acc1.x + acc1.y);
        s += dpp_xor1(s);             // combine K-halves (adjacent lanes)
        const float h2 = tanh_fast(s + b2j);

        // layer 3: partials (kh=1 gives 0) -> per-wave DPP sum
        float p0 = h2 * w3r[0], p1 = h2 * w3r[1], p2 = h2 * w3r[2],
              p3 = h2 * w3r[3], p4 = h2 * w3r[4];
        const float q0 = wave_sum64(p0);
        const float q1 = wave_sum64(p1);
        const float q2 = wave_sum64(p2);
        const float q3 = wave_sum64(p3);
        const float q4 = wave_sum64(p4);
        if (lane == 0) {
            red5[0][w] = q0; red5[1][w] = q1; red5[2][w] = q2;
            red5[3][w] = q3; red5[4][w] = q4;
        }
        __syncthreads();                                   // B2

        f32x4 r0 = *reinterpret_cast<const f32x4*>(&red5[0][0]);
        f32x4 r1 = *reinterpret_cast<const f32x4*>(&red5[1][0]);
        f32x4 r2 = *reinterpret_cast<const f32x4*>(&red5[2][0]);
        f32x4 r3 = *reinterpret_cast<const f32x4*>(&red5[3][0]);
        f32x4 r4 = *reinterpret_cast<const f32x4*>(&red5[4][0]);
        const float o0 = (r0.x + r0.y) + (r0.z + r0.w) + b30;
        const float o1 = (r1.x + r1.y) + (r1.z + r1.w) + b31;
        const float o2 = (r2.x + r2.y) + (r2.z + r2.w) + b32;
        const float o3 = (r3.x + r3.y) + (r3.z + r3.w) + b33;
        const float o4 = (r4.x + r4.y) + (r4.z + r4.w) + b34;

        // epilogue (uniform)
        const float melt = sS0 * sinh_fast(o2);            // relu(step)=step
        d0 = fmaxf(sinh_fast(o3) * sNT, 0.0f) - melt;
        d1 = fmaxf(sinh_fast(o4), 0.0f) + melt
             - sS1 * fmaf(ld, exp_fast(o0), exp_fast(o1));
    };

    // rolling register prefetch (B of step n == A of step n+1)
    float pB = precp[0], tB = temp[0], lB = lday[0];

    for (int cbase = 0; cbase < T - 1; cbase += CHUNK) {
        for (int i = tid; i <= CHUNK; i += 256) {
            int g = cbase + i;
            if (g < T) {
                pr_s[i] = precp[g];
                tm_s[i] = temp[g];
                ld_s[i] = lday[g];
            }
        }
        __syncthreads();

        const int len = min(T - 1 - cbase, CHUNK);
#pragma unroll 1
        for (int l = 0; l < len; ++l) {
            const float pA = pB, tA = tB, lA = lB;
            pB = pr_s[l + 1];
            tB = tm_s[l + 1];
            lB = ld_s[l + 1];
            const float pM = 0.5f * (pA + pB);
            const float tM = 0.5f * (tA + tB);
            const float lM = 0.5f * (lA + lB);

            float k10, k11, k20, k21, k30, k31, k40, k41;
            rhs(S0, S1, pA, tA, lA, k10, k11);                                // h = 1
            rhs(fmaf(0.5f, k10, S0), fmaf(0.5f, k11, S1), pM, tM, lM, k20, k21);
            rhs(fmaf(0.5f, k20, S0), fmaf(0.5f, k21, S1), pM, tM, lM, k30, k31);
            rhs(k30 + S0,            k31 + S1,            pB, tB, lB, k40, k41);

            const float c = 1.0f / 6.0f;
            S0 = S0 + c * (k10 + 2.0f * (k20 + k30) + k40);
            S1 = S1 + c * (k11 + 2.0f * (k21 + k31) + k41);
            if (tid == 0) {
                const int n = cbase + l;
                sol[2 * (n + 1)]     = S0;
                sol[2 * (n + 1) + 1] = S1;
            }
        }
        __syncthreads();   // protect series LDS re-stage vs stragglers
    }
}

// ---------------------------------------------------------------------------
// Output: y[t] = exp(mlp([sol0,sol1,x2,x3])[1]) — fully parallel, tiny.
// ---------------------------------------------------------------------------
extern "C" __global__ void __launch_bounds__(128)
out_kernel(const float* __restrict__ x,
           const float* __restrict__ sol,
           const float* __restrict__ W1, const float* __restrict__ b1,
           const float* __restrict__ W2, const float* __restrict__ b2,
           const float* __restrict__ W3, const float* __restrict__ b3,
           float* __restrict__ y, int T)
{
    const int j    = threadIdx.x;
    const int lane = j & 63;
    const int wv   = j >> 6;

    __shared__ __align__(16) float h1s[128];
    __shared__ float red[2];

    float w1c[4], w2c[128];
#pragma unroll
    for (int i = 0; i < 4; ++i)   w1c[i] = W1[i * 128 + j];
    const float b1j = b1[j];
#pragma unroll
    for (int i = 0; i < 128; ++i) w2c[i] = W2[i * 128 + j];
    const float b2j = b2[j];
    const float w31 = W3[j * 5 + 1];
    const float b31 = b3[1];

#pragma unroll 1
    for (int r = blockIdx.x; r < T; r += gridDim.x) {
        const float z0 = sol[2 * r], z1 = sol[2 * r + 1];
        const float z2 = x[4 * r + 2], z3 = x[4 * r + 3];
        float a = b1j;
        a = fmaf(z0, w1c[0], a);
        a = fmaf(z1, w1c[1], a);
        a = fmaf(z2, w1c[2], a);
        a = fmaf(z3, w1c[3], a);
        h1s[j] = tanh_fast(a);
        __syncthreads();
        float acc0 = 0.f, acc1 = 0.f, acc2 = 0.f, acc3 = 0.f;
#pragma unroll
        for (int i = 0; i < 128; i += 4) {
            const float4 hv = *reinterpret_cast<const float4*>(&h1s[i]);
            acc0 = fmaf(hv.x, w2c[i + 0], acc0);
            acc1 = fmaf(hv.y, w2c[i + 1], acc1);
            acc2 = fmaf(hv.z, w2c[i + 2], acc2);
            acc3 = fmaf(hv.w, w2c[i + 3], acc3);
        }
        const float h2 = tanh_fast(((acc0 + acc1) + (acc2 + acc3)) + b2j);
        float p = h2 * w31;
#pragma unroll
        for (int off = 32; off >= 1; off >>= 1)
            p += __shfl_xor(p, off);
        if (lane == 0) red[wv] = p;
        __syncthreads();
        if (j == 0) y[r] = exp_fast(red[0] + red[1] + b31);
        __syncthreads();
    }
}

// ---------------------------------------------------------------------------
extern "C" void kernel_launch(void* const* d_in, const int* in_sizes, int n_in,
                              void* d_out, int out_size, void* d_ws, size_t ws_size,
                              hipStream_t stream)
{
    const float* x      = (const float*)d_in[0];
    // d_in[1] = t_eval = arange(T) -> h == 1.0
    // d_in[2] = t_grid = arange(T)
    const float* precp  = (const float*)d_in[3];
    const float* temp   = (const float*)d_in[4];
    const float* lday   = (const float*)d_in[5];
    const float* W1     = (const float*)d_in[6];
    const float* b1     = (const float*)d_in[7];
    const float* W2     = (const float*)d_in[8];
    const float* b2     = (const float*)d_in[9];
    const float* W3     = (const float*)d_in[10];
    const float* b3     = (const float*)d_in[11];
    float*       y      = (float*)d_out;
    float*       sol    = (float*)d_ws;      // T*2 floats
    const int    T      = in_sizes[1];

    hipLaunchKernelGGL(scan_kernel, dim3(1), dim3(256), 0, stream,
                       x, precp, temp, lday,
                       W1, b1, W2, b2, W3, b3, sol, T);
    hipLaunchKernelGGL(out_kernel, dim3(256), dim3(128), 0, stream,
                       x, sol, W1, b1, W2, b2, W3, b3, y, T);
}